// Round 7
// baseline (253.100 us; speedup 1.0000x reference)
//
#include <hip/hip_runtime.h>
#include <stdint.h>

// Params computed on-device (grid bounds depend on input VALUES, device-only).
struct Params {
  int am, bm, cm;
  uint32_t Dj, Dk;      // Dj = (2b+1)*(2c+1), Dk = (2c+1)
  uint32_t Mj40, Mk32;  // 32-bit magics: q=(n*Mj40)>>40 (n<2^40/Dj), q=(n*Mk32)>>32 (n<2^32/Dk)
};

__device__ __forceinline__ int iabs_(int x) { return x < 0 ? -x : x; }

// Bit-exact replica of the reference's numpy fp64 nmax(): no fp contraction,
// same op order: cross -> ln=sqrt(dot) -> d=|dot(dr, cr/ln)| -> floor((co+d)/vol*ln)
__device__ __forceinline__ int nmax_ref(double u0, double u1, double u2,
                                        double v0, double v1, double v2,
                                        double dr0, double dr1, double dr2,
                                        double co, double vol) {
#pragma clang fp contract(off)
  double x0 = u1 * v2 - u2 * v1;
  double x1 = u2 * v0 - u0 * v2;
  double x2 = u0 * v1 - u1 * v0;
  double ln = sqrt((x0 * x0 + x1 * x1) + x2 * x2);
  double d  = fabs((dr0 * (x0 / ln) + dr1 * (x1 / ln)) + dr2 * (x2 / ln));
  double f  = floor((co + d) / vol * ln);
  long long n = (long long)f;
  if (n > 100000) n = 100000;
  return (int)n;
}

__global__ void setup_kernel(const float* __restrict__ cell,
                             const float* __restrict__ cutoff,
                             const float* __restrict__ r1,
                             const float* __restrict__ r2,
                             Params* __restrict__ p, int N) {
#pragma clang fp contract(off)
  double a0 = cell[0], a1 = cell[1], a2 = cell[2];
  double b0 = cell[3], b1 = cell[4], b2 = cell[5];
  double c0 = cell[6], c1 = cell[7], c2 = cell[8];
  double dr0 = (double)r2[0] - (double)r1[0];
  double dr1 = (double)r2[1] - (double)r1[1];
  double dr2 = (double)r2[2] - (double)r1[2];
  double co  = (double)cutoff[0];

  double bc0 = b1 * c2 - b2 * c1;
  double bc1 = b2 * c0 - b0 * c2;
  double bc2 = b0 * c1 - b1 * c0;
  double vol = fabs((a0 * bc0 + a1 * bc1) + a2 * bc2);

  int am = nmax_ref(b0, b1, b2, c0, c1, c2, dr0, dr1, dr2, co, vol);
  int bm = nmax_ref(a0, a1, a2, c0, c1, c2, dr0, dr1, dr2, co, vol);
  int cm = nmax_ref(a0, a1, a2, b0, b1, b2, dr0, dr1, dr2, co, vol);

  // Safety net: N = out_size/7 from the harness; if a 1-ulp divergence from
  // numpy shifted a bound, search +-1 perturbations for a product match.
  int fa = am, fb = bm, fc = cm;
  bool found = ((long long)(2 * am + 1) * (2 * bm + 1) * (2 * cm + 1) == (long long)N);
  for (int r = 1; r <= 3 && !found; ++r)
    for (int da = -1; da <= 1 && !found; ++da)
      for (int db = -1; db <= 1 && !found; ++db)
        for (int dc = -1; dc <= 1 && !found; ++dc) {
          if (iabs_(da) + iabs_(db) + iabs_(dc) != r) continue;
          long long A = am + da, B = bm + db, C = cm + dc;
          if (A < 0 || B < 0 || C < 0) continue;
          long long P = (2 * A + 1) * (2 * B + 1) * (2 * C + 1);
          if (P == (long long)N) { fa = (int)A; fb = (int)B; fc = (int)C; found = true; }
        }

  p->am = fa; p->bm = fb; p->cm = fc;
  uint32_t Dk = (uint32_t)(2 * fc + 1);
  uint32_t Dj = (uint32_t)(2 * fb + 1) * Dk;
  p->Dj = Dj; p->Dk = Dk;
  // Round-up 32-bit magics (single v_mul_hi_u32 each in the hot loop):
  //  q = (n*Mj40)>>40 exact for n*Dj < 2^40  (here N*Dj ~ 3.3e11 < 1.1e12 OK)
  //  q = (n*Mk32)>>32 exact for n*Dk < 2^32  (here Dj*Dk ~ 8.1e6 OK)
  p->Mj40 = (uint32_t)(((1ULL << 40) / Dj) + 1);
  p->Mk32 = (uint32_t)(((1ULL << 32) / Dk) + 1);
}

// Direct production of the flat output stream: thread -> 4 aligned float4
// slots; per dword g derive (region, point, component) arithmetically and
// recompute the point. No LDS, no syncthreads, no copy phase, no unaligned
// stores — the store stream is exactly the fillBufferAligned pattern that
// measures 6.7 TB/s on this chip. Redundant compute (~7 point-evals/point)
// totals ~29 us of VALU chip-wide, under the ~34 us store floor.
__global__ __launch_bounds__(256) void periodic_fused(
    const float* __restrict__ cell, const float* __restrict__ cutoff,
    const float* __restrict__ r1, const float* __restrict__ r2,
    const Params* __restrict__ p, float* __restrict__ out, int N) {
  const int tid = threadIdx.x;

  const int am = p->am, bm = p->bm, cm = p->cm;
  const uint32_t Dj = p->Dj, Dk = p->Dk;
  const uint32_t Mj40 = p->Mj40, Mk32 = p->Mk32;

  // wave-uniform scalar loads (L1-cached)
  const float ax = cell[0], ay = cell[1], az = cell[2];
  const float bx = cell[3], by = cell[4], bz = cell[5];
  const float cx = cell[6], cy = cell[7], cz = cell[8];
  const float drx = r2[0] - r1[0], dry = r2[1] - r1[1], drz = r2[2] - r1[2];
  const float co  = cutoff[0];
  const float co2 = co * co;

  const size_t N3 = (size_t)3 * (size_t)N;
  const size_t N6 = 2 * N3;
  const size_t N7 = N6 + (size_t)N;
  const size_t f4_total = (N7 + 3) >> 2;

  const size_t w0 = (size_t)blockIdx.x * 1024 + (size_t)tid;

#pragma unroll
  for (int u = 0; u < 4; ++u) {
    const size_t w = w0 + (size_t)(u << 8);
    if (w >= f4_total) continue;
    const size_t g0 = w << 2;

    float vals[4];
#pragma unroll
    for (int j = 0; j < 4; ++j) {
      const size_t g = g0 + (size_t)j;
      const bool rB = g >= N3;
      const bool rC = g >= N6;
      // region-local dword offset (fits u32: < 3N ~ 2^25)
      uint32_t gp = (uint32_t)(g - (rB ? N3 : 0) - (rC ? N3 : 0));
      // point/component within region (exact /3 for all u32)
      uint32_t pA = (uint32_t)(((uint64_t)gp * 0xAAAAAAABULL) >> 33);
      uint32_t c  = gp - 3u * pA;
      uint32_t pp = rC ? gp : pA;        // mask region: gp IS the point index
      // point -> (i,j,k) via 32-bit magics (mul_hi + shift each)
      uint32_t qi  = (uint32_t)(((uint64_t)pp  * Mj40) >> 40);
      uint32_t rem = pp - qi * Dj;
      uint32_t qj  = (uint32_t)(((uint64_t)rem * Mk32) >> 32);
      uint32_t qk  = rem - qj * Dk;

      float fi = (float)((int)qi - am);
      float fj = (float)((int)qj - bm);
      float fk = (float)((int)qk - cm);

      // disp = ijk @ cell in f32, XLA-style k-ascending fmuladd accumulation
      float vx = fmaf(fk, cx, fmaf(fj, bx, fi * ax)) + drx;
      float vy = fmaf(fk, cy, fmaf(fj, by, fi * ay)) + dry;
      float vz = fmaf(fk, cz, fmaf(fj, bz, fi * az)) + drz;

      float s = fmaf(vz, vz, fmaf(vy, vy, vx * vx));
      bool  m = s < co2;

      float s0 = rB ? fi : vx;
      float s1 = rB ? fj : vy;
      float s2 = rB ? fk : vz;
      float t  = (c == 0u) ? s0 : (c == 1u) ? s1 : s2;
      t = rC ? 1.0f : t;
      vals[j] = m ? t : 0.0f;
    }

    if (g0 + 4 <= N7) {
      *reinterpret_cast<float4*>(out + g0) =
          make_float4(vals[0], vals[1], vals[2], vals[3]);
    } else {
#pragma unroll
      for (int j = 0; j < 4; ++j)
        if (g0 + (size_t)j < N7) out[g0 + (size_t)j] = vals[j];
    }
  }
}

extern "C" void kernel_launch(void* const* d_in, const int* in_sizes, int n_in,
                              void* d_out, int out_size, void* d_ws, size_t ws_size,
                              hipStream_t stream) {
  const float* cell   = (const float*)d_in[0];
  const float* cutoff = (const float*)d_in[1];
  const float* r1     = (const float*)d_in[2];
  const float* r2     = (const float*)d_in[3];
  float* out = (float*)d_out;

  int N = out_size / 7;
  Params* p = (Params*)d_ws;

  setup_kernel<<<1, 1, 0, stream>>>(cell, cutoff, r1, r2, p, N);

  size_t f4_total = ((size_t)out_size + 3) >> 2;
  int blocks = (int)((f4_total + 1023) >> 10);   // 1024 f4 slots per block
  periodic_fused<<<blocks, 256, 0, stream>>>(cell, cutoff, r1, r2, p, out, N);
}

// Round 9
// 232.548 us; speedup vs baseline: 1.0884x; 1.0884x over previous
//
#include <hip/hip_runtime.h>
#include <stdint.h>

// Params computed on-device (grid bounds depend on input VALUES, device-only).
struct Params {
  int am, bm, cm;
  uint32_t Dj, Dk;      // Dj = (2b+1)*(2c+1), Dk = (2c+1)
  uint32_t Mj40, Mk32;  // magics: q=(n*Mj40)>>40 (ok: (n+1)*Dj<2^40), q=(n*Mk32)>>32 (ok: Dj*Dk<2^32)
};

__device__ __forceinline__ int iabs_(int x) { return x < 0 ? -x : x; }

// Bit-exact replica of the reference's numpy fp64 nmax(): no fp contraction,
// same op order: cross -> ln=sqrt(dot) -> d=|dot(dr, cr/ln)| -> floor((co+d)/vol*ln)
__device__ __forceinline__ int nmax_ref(double u0, double u1, double u2,
                                        double v0, double v1, double v2,
                                        double dr0, double dr1, double dr2,
                                        double co, double vol) {
#pragma clang fp contract(off)
  double x0 = u1 * v2 - u2 * v1;
  double x1 = u2 * v0 - u0 * v2;
  double x2 = u0 * v1 - u1 * v0;
  double ln = sqrt((x0 * x0 + x1 * x1) + x2 * x2);
  double d  = fabs((dr0 * (x0 / ln) + dr1 * (x1 / ln)) + dr2 * (x2 / ln));
  double f  = floor((co + d) / vol * ln);
  long long n = (long long)f;
  if (n > 100000) n = 100000;
  return (int)n;
}

__global__ void setup_kernel(const float* __restrict__ cell,
                             const float* __restrict__ cutoff,
                             const float* __restrict__ r1,
                             const float* __restrict__ r2,
                             Params* __restrict__ p, int N) {
#pragma clang fp contract(off)
  double a0 = cell[0], a1 = cell[1], a2 = cell[2];
  double b0 = cell[3], b1 = cell[4], b2 = cell[5];
  double c0 = cell[6], c1 = cell[7], c2 = cell[8];
  double dr0 = (double)r2[0] - (double)r1[0];
  double dr1 = (double)r2[1] - (double)r1[1];
  double dr2 = (double)r2[2] - (double)r1[2];
  double co  = (double)cutoff[0];

  double bc0 = b1 * c2 - b2 * c1;
  double bc1 = b2 * c0 - b0 * c2;
  double bc2 = b0 * c1 - b1 * c0;
  double vol = fabs((a0 * bc0 + a1 * bc1) + a2 * bc2);

  int am = nmax_ref(b0, b1, b2, c0, c1, c2, dr0, dr1, dr2, co, vol);
  int bm = nmax_ref(a0, a1, a2, c0, c1, c2, dr0, dr1, dr2, co, vol);
  int cm = nmax_ref(a0, a1, a2, b0, b1, b2, dr0, dr1, dr2, co, vol);

  // Safety net: N = out_size/7 from the harness; if a 1-ulp divergence from
  // numpy shifted a bound, search +-1 perturbations for a product match.
  int fa = am, fb = bm, fc = cm;
  bool found = ((long long)(2 * am + 1) * (2 * bm + 1) * (2 * cm + 1) == (long long)N);
  for (int r = 1; r <= 3 && !found; ++r)
    for (int da = -1; da <= 1 && !found; ++da)
      for (int db = -1; db <= 1 && !found; ++db)
        for (int dc = -1; dc <= 1 && !found; ++dc) {
          if (iabs_(da) + iabs_(db) + iabs_(dc) != r) continue;
          long long A = am + da, B = bm + db, C = cm + dc;
          if (A < 0 || B < 0 || C < 0) continue;
          long long P = (2 * A + 1) * (2 * B + 1) * (2 * C + 1);
          if (P == (long long)N) { fa = (int)A; fb = (int)B; fc = (int)C; found = true; }
        }

  p->am = fa; p->bm = fb; p->cm = fc;
  uint32_t Dk = (uint32_t)(2 * fc + 1);
  uint32_t Dj = (uint32_t)(2 * fb + 1) * Dk;
  p->Dj = Dj; p->Dk = Dk;
  p->Mj40 = (uint32_t)(((1ULL << 40) / Dj) + 1);
  p->Mk32 = (uint32_t)(((1ULL << 32) / Dk) + 1);
}

// Runtime constants passed through registers to the helpers.
struct Cst {
  float ax, ay, az, bx, by, bz, cx, cy, cz, drx, dry, drz, co2;
  int am, bm, cm;
  uint32_t Dj, Dk, Mj40, Mk32;
};

// Full point evaluation: p -> (i,j,k) -> disp+dr, mask. All u32 index math.
__device__ __forceinline__ void pchain(const Cst& C, uint32_t p,
                                       float& x, float& y, float& z, bool& m,
                                       float& fi, float& fj, float& fk) {
  uint32_t qi  = (uint32_t)(((uint64_t)p * C.Mj40) >> 40);
  uint32_t rem = p - qi * C.Dj;
  uint32_t qj  = (uint32_t)(((uint64_t)rem * C.Mk32) >> 32);
  uint32_t qk  = rem - qj * C.Dk;
  fi = (float)((int)qi - C.am);
  fj = (float)((int)qj - C.bm);
  fk = (float)((int)qk - C.cm);
  x = fmaf(fk, C.cx, fmaf(fj, C.bx, fi * C.ax)) + C.drx;
  y = fmaf(fk, C.cy, fmaf(fj, C.by, fi * C.ay)) + C.dry;
  z = fmaf(fk, C.cz, fmaf(fj, C.bz, fi * C.az)) + C.drz;
  float s = fmaf(z, z, fmaf(y, y, x * x));
  m = s < C.co2;
}

// 4 consecutive dwords of region A (vectors) or B (indices): exactly the
// components of points p0 and p0+1 -> only 2 chains per 16B slot.
__device__ __forceinline__ float4 slotAB(const Cst& C, uint32_t lp, bool isB) {
  uint32_t p0 = (uint32_t)(((uint64_t)lp * 0xAAAAAAABULL) >> 33);  // lp/3
  uint32_t c0 = lp - 3u * p0;
  float x0, y0, z0, fi0, fj0, fk0, x1, y1, z1, fi1, fj1, fk1;
  bool m0, m1;
  pchain(C, p0,      x0, y0, z0, m0, fi0, fj0, fk0);
  pchain(C, p0 + 1u, x1, y1, z1, m1, fi1, fj1, fk1);   // p0+1 <= N-1 in fast path
  float a0 = isB ? fi0 : x0, a1 = isB ? fj0 : y0, a2 = isB ? fk0 : z0;
  float b0 = isB ? fi1 : x1, b1 = isB ? fj1 : y1, b2 = isB ? fk1 : z1;
  a0 = m0 ? a0 : 0.f; a1 = m0 ? a1 : 0.f; a2 = m0 ? a2 : 0.f;
  b0 = m1 ? b0 : 0.f; b1 = m1 ? b1 : 0.f; b2 = m1 ? b2 : 0.f;
  float4 r;
  r.x = (c0 == 0u) ? a0 : ((c0 == 1u) ? a1 : a2);
  r.y = (c0 == 0u) ? a1 : ((c0 == 1u) ? a2 : b0);
  r.z = (c0 == 0u) ? a2 : ((c0 == 1u) ? b0 : b1);
  r.w = (c0 == 0u) ? b0 : ((c0 == 1u) ? b1 : b2);
  return r;
}

// 4 consecutive dwords of region C (mask): 4 points.
__device__ __forceinline__ float4 slotC(const Cst& C, uint32_t lp) {
  float x, y, z, fi, fj, fk;
  bool m;
  float4 r;
  pchain(C, lp + 0u, x, y, z, m, fi, fj, fk); r.x = m ? 1.f : 0.f;
  pchain(C, lp + 1u, x, y, z, m, fi, fj, fk); r.y = m ? 1.f : 0.f;
  pchain(C, lp + 2u, x, y, z, m, fi, fj, fk); r.z = m ? 1.f : 0.f;
  pchain(C, lp + 3u, x, y, z, m, fi, fj, fk); r.w = m ? 1.f : 0.f;
  return r;
}

// General per-dword path for the ~3 straddle/tail slots chip-wide.
__device__ __forceinline__ float dwordgen(const Cst& C, uint32_t g,
                                          uint32_t N3, uint32_t N6) {
  bool rB = g >= N3, rC = g >= N6;
  uint32_t gp = g - (rB ? N3 : 0u) - (rC ? N3 : 0u);
  uint32_t pA = (uint32_t)(((uint64_t)gp * 0xAAAAAAABULL) >> 33);
  uint32_t c  = gp - 3u * pA;
  uint32_t pp = rC ? gp : pA;
  float x, y, z, fi, fj, fk;
  bool m;
  pchain(C, pp, x, y, z, m, fi, fj, fk);
  float s0 = rB ? fi : x, s1 = rB ? fj : y, s2 = rB ? fk : z;
  float t  = (c == 0u) ? s0 : ((c == 1u) ? s1 : s2);
  t = rC ? 1.0f : t;
  return m ? t : 0.0f;
}

// Direct flat-stream production, lean version: one aligned float4 per 16
// output bytes (the fillBufferAligned pattern = 6.7 TB/s proven), u32 index
// math only, 2 chains per vec/idx slot (4 for mask slots), region branches
// uniform per block except ~3 straddle blocks.
__global__ __launch_bounds__(256) void periodic_fused2(
    const float* __restrict__ cell, const float* __restrict__ cutoff,
    const float* __restrict__ r1, const float* __restrict__ r2,
    const Params* __restrict__ p, float* __restrict__ out, int N) {
  Cst C;
  C.ax = cell[0]; C.ay = cell[1]; C.az = cell[2];
  C.bx = cell[3]; C.by = cell[4]; C.bz = cell[5];
  C.cx = cell[6]; C.cy = cell[7]; C.cz = cell[8];
  C.drx = r2[0] - r1[0]; C.dry = r2[1] - r1[1]; C.drz = r2[2] - r1[2];
  float co = cutoff[0];
  C.co2 = co * co;
  C.am = p->am; C.bm = p->bm; C.cm = p->cm;
  C.Dj = p->Dj; C.Dk = p->Dk; C.Mj40 = p->Mj40; C.Mk32 = p->Mk32;

  const uint32_t Nu = (uint32_t)N;
  const uint32_t N3 = 3u * Nu, N6 = 6u * Nu, N7 = 7u * Nu;
  const uint32_t f4_total = (N7 + 3u) >> 2;
  const uint32_t w0 = blockIdx.x * 1024u + threadIdx.x;

#pragma unroll
  for (int u = 0; u < 4; ++u) {
    const uint32_t w = w0 + ((uint32_t)u << 8);
    if (w >= f4_total) continue;
    const uint32_t g0 = w << 2;

    const bool strA = (g0 < N3) && (g0 + 3u >= N3);
    const bool strB = (g0 < N6) && (g0 + 3u >= N6);
    const bool tail = (g0 + 4u > N7);

    if (strA || strB || tail) {
#pragma unroll
      for (int j = 0; j < 4; ++j) {
        uint32_t g = g0 + (uint32_t)j;
        if (g < N7) out[g] = dwordgen(C, g, N3, N6);
      }
    } else if (g0 >= N6) {
      *reinterpret_cast<float4*>(out + g0) = slotC(C, g0 - N6);
    } else if (g0 >= N3) {
      *reinterpret_cast<float4*>(out + g0) = slotAB(C, g0 - N3, true);
    } else {
      *reinterpret_cast<float4*>(out + g0) = slotAB(C, g0, false);
    }
  }
}

extern "C" void kernel_launch(void* const* d_in, const int* in_sizes, int n_in,
                              void* d_out, int out_size, void* d_ws, size_t ws_size,
                              hipStream_t stream) {
  const float* cell   = (const float*)d_in[0];
  const float* cutoff = (const float*)d_in[1];
  const float* r1     = (const float*)d_in[2];
  const float* r2     = (const float*)d_in[3];
  float* out = (float*)d_out;

  int N = out_size / 7;
  Params* p = (Params*)d_ws;

  setup_kernel<<<1, 1, 0, stream>>>(cell, cutoff, r1, r2, p, N);

  size_t f4_total = ((size_t)out_size + 3) >> 2;
  int blocks = (int)((f4_total + 1023) >> 10);   // 1024 f4 slots per block
  periodic_fused2<<<blocks, 256, 0, stream>>>(cell, cutoff, r1, r2, p, out, N);
}